// Round 15
// baseline (110.798 us; speedup 1.0000x reference)
//
#include <hip/hip_runtime.h>
#include <math.h>

// Problem constants: B=32, S=2048, C=16, E=8, H=16
#define NB 32
#define NS 2048
#define NC 16
#define NE 8
#define NH 16
#define KSL 64            // K-slices for gate partial GEMM (32 s per slice)
#define WPAD 68           // padded W-row length in LDS (16B-aligned, bank-rotated)

// ---------------------------------------------------------------------------
// Kernel A1: gate partial sums, LDS-staged, full occupancy.
// (byte-identical to round-14 measured build)
// ---------------------------------------------------------------------------
__global__ __launch_bounds__(256) void gate_partial(
    const float* __restrict__ x,
    const float* __restrict__ Wm,
    const float* __restrict__ Wn,
    float* __restrict__ partial)
{
    const int b  = blockIdx.y;
    const int sl = blockIdx.x;
    const int t  = threadIdx.x;

    __shared__ float xs[32 * 32];       // 4 KB
    __shared__ float ws[16 * WPAD];     // 4.35 KB

    {
        const float* __restrict__ gx = x + b * (NS * NC * 2) + sl * 32 * 32;
        *(float4*)(xs + 4 * t) = *(const float4*)(gx + 4 * t);
    }
    {
        const int row  = t >> 4;
        const int col4 = t & 15;
        const float* __restrict__ gw =
            ((row < 8) ? (Wm + row * (2 * NS)) : (Wn + (row - 8) * (2 * NS)))
            + sl * 64 + col4 * 4;
        *(float4*)(ws + row * WPAD + col4 * 4) = *(const float4*)gw;
    }
    __syncthreads();

    const int c = t & 15;
    const int e = t >> 4;
    const float* __restrict__ wrow = ws + e * WPAD;
    const float* __restrict__ xcol = xs + 2 * c;

    float a0 = 0.f, a1 = 0.f, a2 = 0.f, a3 = 0.f;
#pragma unroll
    for (int i = 0; i < 32; i += 4) {
        const float2 w0 = *(const float2*)(wrow + 2 * (i + 0));
        const float2 w1 = *(const float2*)(wrow + 2 * (i + 1));
        const float2 w2 = *(const float2*)(wrow + 2 * (i + 2));
        const float2 w3 = *(const float2*)(wrow + 2 * (i + 3));
        const float2 x0 = *(const float2*)(xcol + 32 * (i + 0));
        const float2 x1 = *(const float2*)(xcol + 32 * (i + 1));
        const float2 x2 = *(const float2*)(xcol + 32 * (i + 2));
        const float2 x3 = *(const float2*)(xcol + 32 * (i + 3));
        a0 = fmaf(x0.x, w0.x, a0); a0 = fmaf(x0.y, w0.y, a0);
        a1 = fmaf(x1.x, w1.x, a1); a1 = fmaf(x1.y, w1.y, a1);
        a2 = fmaf(x2.x, w2.x, a2); a2 = fmaf(x2.y, w2.y, a2);
        a3 = fmaf(x3.x, w3.x, a3); a3 = fmaf(x3.y, w3.y, a3);
    }
    const float acc = (a0 + a1) + (a2 + a3);
    partial[(((b * KSL) + sl) * 16 + e) * 16 + c] = acc;
}

// ---------------------------------------------------------------------------
// Kernel A2: gate finalize, one wave per row. (byte-identical to round-14)
// ---------------------------------------------------------------------------
__global__ __launch_bounds__(64) void gate_final(
    const float* __restrict__ partial,
    const float* __restrict__ bm, const float* __restrict__ bn,
    const int* __restrict__ kptr,
    float* __restrict__ gates)
{
    const int r = blockIdx.x;
    const int b = r >> 4;
    const int c = r & 15;
    const int l = threadIdx.x;
    const int e16    = l & 15;
    const int sl_grp = l >> 4;

    float v = 0.f;
#pragma unroll
    for (int j = 0; j < 16; ++j) {
        const int sl = sl_grp * 16 + j;
        v += partial[(((b * KSL) + sl) * 16 + e16) * 16 + c];
    }
    v += __shfl_xor(v, 16);
    v += __shfl_xor(v, 32);

    const int e = l & 7;
    const float gm  = __shfl(v, e);
    const float gnv = __shfl(v, e + 8);
    const float gn  = gnv + bn[e];
    const float sp  = (gn > 20.f) ? gn : __logf(1.f + __expf(gn));
    const float g   = gm + bm[e] + sp;

    float garr[NE];
#pragma unroll
    for (int o = 0; o < NE; ++o) garr[o] = __shfl(g, o);

    float s[NE];
#pragma unroll
    for (int o = 0; o < NE; ++o) s[o] = garr[o];
#define CSWP(i, j) { float lo = fminf(s[i], s[j]); float hi = fmaxf(s[i], s[j]); s[i] = lo; s[j] = hi; }
    CSWP(0,1) CSWP(2,3) CSWP(4,5) CSWP(6,7)
    CSWP(0,2) CSWP(1,3) CSWP(4,6) CSWP(5,7)
    CSWP(1,2) CSWP(5,6)
    CSWP(0,4) CSWP(1,5) CSWP(2,6) CSWP(3,7)
    CSWP(2,4) CSWP(3,5)
    CSWP(1,2) CSWP(3,4) CSWP(5,6)
#undef CSWP

    const int k = *kptr;
    const float kth = s[NE - 1 - k];
    const float mx  = s[NE - 1];
    float denom = 0.f;
    float keep_mine = 0.f;
#pragma unroll
    for (int o = 0; o < NE; ++o) {
        const float ex = (garr[o] > kth) ? __expf(garr[o] - mx) : 0.f;
        denom += ex;
        if (o == e) keep_mine = ex;
    }
    if (l < NE) gates[r * NE + l] = keep_mine / denom;
}

// ---------------------------------------------------------------------------
// Fast nonlinearities (native exp/log based; abs err <= ~2e-6, budget 0.335)
// ---------------------------------------------------------------------------
template <int E> __device__ __forceinline__ float nlin(float v);
template <> __device__ __forceinline__ float nlin<0>(float v) { return fmaxf(v, 0.f); }   // relu
template <> __device__ __forceinline__ float nlin<1>(float v) {                           // tanh
    const float t = __expf(2.f * fminf(v, 15.f));
    return __fdividef(t - 1.f, t + 1.f);
}
template <> __device__ __forceinline__ float nlin<2>(float v) {                           // elu
    return v > 0.f ? v : (__expf(v) - 1.f);
}
template <> __device__ __forceinline__ float nlin<3>(float v) {                           // silu
    return __fdividef(v, 1.f + __expf(-v));
}
template <> __device__ __forceinline__ float nlin<4>(float v) { return v; }               // none
template <> __device__ __forceinline__ float nlin<5>(float v) {                           // gelu (erf, A&S 7.1.26)
    const float u  = v * 0.70710678118654752f;
    const float au = fabsf(u);
    const float t  = __fdividef(1.f, fmaf(0.3275911f, au, 1.f));
    float p = fmaf(1.061405429f, t, -1.453152027f);
    p = fmaf(p, t, 1.421413741f);
    p = fmaf(p, t, -0.284496736f);
    p = fmaf(p, t, 0.254829592f);
    const float y = 1.f - p * t * __expf(-u * u);
    const float erfv = copysignf(y, u);
    return 0.5f * v * (1.f + erfv);
}
template <> __device__ __forceinline__ float nlin<6>(float v) {                           // selu
    return 1.0507009873554805f * (v > 0.f ? v : 1.6732632423543772f * (__expf(v) - 1.f));
}
template <> __device__ __forceinline__ float nlin<7>(float v) {                           // softplus
    return (v > 20.f) ? v : __logf(1.f + __expf(v));
}

// Weights read from LDS (broadcast, compile-time offsets): per h one
// ds_read_b128 {w0,w1,w2,b1} + one ds_read_b64 {u0,u1}. Zero global traffic.
template <int E>
__device__ __forceinline__ void expert_accum2(
    const float (&xx)[2], const float (&xy)[2], const float (&am)[2], float ge,
    const float (*__restrict__ pk1)[NH][4],
    const float (*__restrict__ pk2)[NH][2],
    const float (*__restrict__ pb2)[2],
    float (&ot0)[2], float (&ot1)[2])
{
    if (ge != 0.f) {   // wave-uniform (gate row shared by whole wave) -> execz skip
        float a0[2] = {0.f, 0.f}, a1[2] = {0.f, 0.f};
#pragma unroll
        for (int h = 0; h < NH; ++h) {
            const float4 w = *(const float4*)pk1[E][h];   // {w0,w1,w2,b1}
            const float2 u = *(const float2*)pk2[E][h];   // {u0,u1}
#pragma unroll
            for (int j = 0; j < 2; ++j) {
                const float pre = fmaf(w.x, xx[j], fmaf(w.y, xy[j], fmaf(w.z, am[j], w.w)));
                const float a = nlin<E>(pre);
                a0[j] = fmaf(u.x, a, a0[j]);
                a1[j] = fmaf(u.y, a, a1[j]);
            }
        }
        const float c0 = pb2[E][0];
        const float c1 = pb2[E][1];
#pragma unroll
        for (int j = 0; j < 2; ++j) {
            ot0[j] = fmaf(ge, a0[j] + c0, ot0[j]);
            ot1[j] = fmaf(ge, a1[j] + c1, ot1[j]);
        }
    }
}

// ---------------------------------------------------------------------------
// Kernel B: out[b,s,c,t] = sum_e gate[b*16+c,e] * Expert_e(x[b, c*128+(s>>4), s&15, :])
// CHANGE vs round-14: all expert weights staged in LDS once per block
// (784 floats, repacked for b128/b64 broadcast reads); hot loop has zero
// global loads. Everything else identical.
// ---------------------------------------------------------------------------
__global__ __launch_bounds__(1024) void expert_kernel(
    const float* __restrict__ x,
    const float* __restrict__ W1, const float* __restrict__ b1,
    const float* __restrict__ W2, const float* __restrict__ b2,
    const float* __restrict__ gates,
    float* __restrict__ out)
{
    const int b  = blockIdx.y;
    const int s0 = blockIdx.x * 128;
    const int t  = threadIdx.x;
    const int c    = t >> 6;
    const int lane = t & 63;

    __shared__ float pk1[NE][NH][4];   // {W1[e,h,0..2], b1[e,h]}
    __shared__ float pk2[NE][NH][2];   // {W2[e,0,h], W2[e,1,h]}
    __shared__ float pb2[NE][2];
    __shared__ float lds[128 * 34];    // output staging

    // ---- stage weights once per block (128+16 threads active) ----
    if (t < 128) {
        const int e = t >> 4, h = t & 15;
        pk1[e][h][0] = W1[(e * NH + h) * 3 + 0];
        pk1[e][h][1] = W1[(e * NH + h) * 3 + 1];
        pk1[e][h][2] = W1[(e * NH + h) * 3 + 2];
        pk1[e][h][3] = b1[e * NH + h];
        pk2[e][h][0] = W2[e * 2 * NH + h];
        pk2[e][h][1] = W2[e * 2 * NH + NH + h];
    } else if (t < 144) {
        const int i = t - 128;                 // 0..15
        pb2[i >> 1][i & 1] = b2[i];
    }

    float g[NE];
    const float* grow = gates + (b * NC + c) * NE;
#pragma unroll
    for (int e = 0; e < NE; ++e) g[e] = grow[e];

    float xx[2], xy[2], am[2], ot0[2] = {0.f, 0.f}, ot1[2] = {0.f, 0.f};
#pragma unroll
    for (int j = 0; j < 2; ++j) {
        const int s = s0 + lane + 64 * j;
        const float2 xv = *(const float2*)(x + b * (NS * NC * 2)
                                             + (c * 128 + (s >> 4)) * (NC * 2)
                                             + (s & 15) * 2);
        xx[j] = xv.x; xy[j] = xv.y;
        am[j] = sqrtf(fmaf(xv.x, xv.x, xv.y * xv.y));
    }
    __syncthreads();   // weights staged

    expert_accum2<0>(xx, xy, am, g[0], pk1, pk2, pb2, ot0, ot1);
    expert_accum2<1>(xx, xy, am, g[1], pk1, pk2, pb2, ot0, ot1);
    expert_accum2<2>(xx, xy, am, g[2], pk1, pk2, pb2, ot0, ot1);
    expert_accum2<3>(xx, xy, am, g[3], pk1, pk2, pb2, ot0, ot1);
    expert_accum2<4>(xx, xy, am, g[4], pk1, pk2, pb2, ot0, ot1);
    expert_accum2<5>(xx, xy, am, g[5], pk1, pk2, pb2, ot0, ot1);
    expert_accum2<6>(xx, xy, am, g[6], pk1, pk2, pb2, ot0, ot1);
    expert_accum2<7>(xx, xy, am, g[7], pk1, pk2, pb2, ot0, ot1);

#pragma unroll
    for (int j = 0; j < 2; ++j) {
        const int sl = lane + 64 * j;
        lds[sl * 34 + c * 2 + 0] = ot0[j];
        lds[sl * 34 + c * 2 + 1] = ot1[j];
    }
    __syncthreads();

#pragma unroll
    for (int j = 0; j < 2; ++j) {
        const int m  = t + 1024 * j;
        const int sl = m >> 4;
        const int cc = m & 15;
        float2 v = make_float2(lds[sl * 34 + cc * 2], lds[sl * 34 + cc * 2 + 1]);
        *(float2*)(out + b * (NS * NC * 2) + (s0 + sl) * (NC * 2) + cc * 2) = v;
    }
}

extern "C" void kernel_launch(void* const* d_in, const int* in_sizes, int n_in,
                              void* d_out, int out_size, void* d_ws, size_t ws_size,
                              hipStream_t stream) {
    const float* x  = (const float*)d_in[0];
    const float* Wm = (const float*)d_in[1];
    const float* bm = (const float*)d_in[2];
    const float* Wn = (const float*)d_in[3];
    const float* bn = (const float*)d_in[4];
    const float* W1 = (const float*)d_in[5];
    const float* b1 = (const float*)d_in[6];
    const float* W2 = (const float*)d_in[7];
    const float* b2 = (const float*)d_in[8];
    const int*   kp = (const int*)d_in[9];
    float* out     = (float*)d_out;
    float* gates   = (float*)d_ws;                        // 512*8 floats   = 16 KB
    float* partial = (float*)d_ws + 4096;                 // 32*64*16*16 fl = 2 MB

    dim3 gp_grid(KSL, NB);
    gate_partial<<<gp_grid, 256, 0, stream>>>(x, Wm, Wn, partial);
    gate_final<<<NB * NC, 64, 0, stream>>>(partial, bm, bn, kp, gates);

    dim3 grid(NS / 128, NB);
    expert_kernel<<<grid, 1024, 0, stream>>>(x, W1, b1, W2, b2, gates, out);
}